// Round 2
// baseline (541.424 us; speedup 1.0000x reference)
//
#include <hip/hip_runtime.h>
#include <math.h>
#include <float.h>

#define N_NODES 50000
#define N_EDGES 800000
#define D 64
#define NDIR (2 * N_EDGES)

static inline size_t align_up(size_t x, size_t a) { return (x + a - 1) & ~(a - 1); }

// rows = concat(e0, e1) = ei[j] for j in [0, 2E)
// cols = concat(e1, e0) = ei[j+E] (j<E) else ei[j-E]

__global__ void k_deg(const int* __restrict__ ei, int* __restrict__ deg) {
    int j = blockIdx.x * blockDim.x + threadIdx.x;
    if (j >= NDIR) return;
    atomicAdd(&deg[ei[j]], 1);
}

__global__ void k_scan1(const int* __restrict__ deg, int* __restrict__ offs,
                        int* __restrict__ bsum) {
    __shared__ int s[1024];
    int tid = threadIdx.x;
    int i = blockIdx.x * 1024 + tid;
    int v = (i < N_NODES) ? deg[i] : 0;
    s[tid] = v;
    __syncthreads();
    for (int d = 1; d < 1024; d <<= 1) {
        int t = (tid >= d) ? s[tid - d] : 0;
        __syncthreads();
        v += t;
        s[tid] = v;
        __syncthreads();
    }
    if (i < N_NODES) offs[i + 1] = v;   // inclusive within block
    if (tid == 1023) bsum[blockIdx.x] = v;
}

__global__ void k_scan2(int* __restrict__ bsum, int nb) {
    __shared__ int s[64];
    int tid = threadIdx.x;
    if (tid < nb) s[tid] = bsum[tid];
    __syncthreads();
    if (tid == 0) {
        int run = 0;
        for (int b = 0; b < nb; ++b) { int t = s[b]; s[b] = run; run += t; }
    }
    __syncthreads();
    if (tid < nb) bsum[tid] = s[tid];
}

// offs[i+1] += bsum[block(i)]; offs[0]=0; also seed cur[i] = final offs[i]
__global__ void k_scan3(int* __restrict__ offs, const int* __restrict__ bsum,
                        int* __restrict__ cur) {
    int i = blockIdx.x * blockDim.x + threadIdx.x;
    if (i == 0) offs[0] = 0;
    if (i < N_NODES) {
        int v = offs[i + 1] + bsum[i >> 10];
        offs[i + 1] = v;
        // cur[i] = offs[i] (exclusive start). offs[i] for i>0 is written by the
        // thread handling i-1; recompute it locally instead to avoid a dependency:
        // offs[i] = (i==0) ? 0 : scan-result — we can't read it safely, so seed
        // cur from the same arithmetic: handled in k_seed below.
    }
}

__global__ void k_seed(const int* __restrict__ offs, int* __restrict__ cur) {
    int i = blockIdx.x * blockDim.x + threadIdx.x;
    if (i < N_NODES) cur[i] = offs[i];
}

__global__ void k_fill(const int* __restrict__ ei, int* __restrict__ cur,
                       int* __restrict__ adj) {
    int j = blockIdx.x * blockDim.x + threadIdx.x;
    if (j >= NDIR) return;
    int row = ei[j];
    int col = (j < N_EDGES) ? ei[j + N_EDGES] : ei[j - N_EDGES];
    int pos = atomicAdd(&cur[row], 1);
    adj[pos] = col;
}

// One wave per node: sum/max aggregation + fused attention mix.
// Writes x = h + w0*agg_sum + w1*agg_max.
__global__ void k_agg(const float* __restrict__ h, const int* __restrict__ offs,
                      const int* __restrict__ adj, const float* __restrict__ att_w,
                      const float* __restrict__ att_b, float* __restrict__ xbuf) {
    int wid = (blockIdx.x * blockDim.x + threadIdx.x) >> 6;  // node id (grid sized exactly)
    int lane = threadIdx.x & 63;
    int start = offs[wid], end = offs[wid + 1];
    float sum = 0.f, mx = -FLT_MAX;
    int e = start;
    for (; e + 4 <= end; e += 4) {
        int c0 = adj[e], c1 = adj[e + 1], c2 = adj[e + 2], c3 = adj[e + 3];
        float v0 = h[c0 * D + lane];
        float v1 = h[c1 * D + lane];
        float v2 = h[c2 * D + lane];
        float v3 = h[c3 * D + lane];
        sum += v0 + v1 + v2 + v3;
        mx = fmaxf(mx, fmaxf(fmaxf(v0, v1), fmaxf(v2, v3)));
    }
    for (; e < end; ++e) {
        float v = h[adj[e] * D + lane];
        sum += v;
        mx = fmaxf(mx, v);
    }
    if (end == start) mx = 0.f;   // deg==0 -> agg_max masked to 0 (sum already 0)

    // scores = [sum | max] @ att_w + att_b  (att_w is (128,2) row-major)
    float aw00 = att_w[lane * 2 + 0], aw01 = att_w[lane * 2 + 1];
    float aw10 = att_w[(D + lane) * 2 + 0], aw11 = att_w[(D + lane) * 2 + 1];
    float p0 = sum * aw00 + mx * aw10;
    float p1 = sum * aw01 + mx * aw11;
    for (int o = 32; o > 0; o >>= 1) {
        p0 += __shfl_xor(p0, o);
        p1 += __shfl_xor(p1, o);
    }
    float s0 = p0 + att_b[0], s1 = p1 + att_b[1];
    float m = fmaxf(s0, s1);
    float e0 = expf(s0 - m), e1 = expf(s1 - m);
    float inv = 1.f / (e0 + e1);
    float w0 = e0 * inv, w1 = e1 * inv;
    xbuf[wid * D + lane] = h[wid * D + lane] + w0 * sum + w1 * mx;
}

// Fused 3-layer MLP on 64-row tiles. LDS: x-tile, y-tile, one weight buffer.
__global__ __launch_bounds__(256) void k_dense(const float* __restrict__ xbuf,
        const float* __restrict__ w1, const float* __restrict__ b1,
        const float* __restrict__ w2, const float* __restrict__ b2,
        const float* __restrict__ w3, const float* __restrict__ b3,
        float* __restrict__ out) {
    __shared__ float xt[64 * 64];
    __shared__ float yt[64 * 64];
    __shared__ float wb[64 * 64];
    int tid = threadIdx.x;
    int base = blockIdx.x * 64;

    for (int i = tid; i < 64 * 64; i += 256) {
        int r = base + (i >> 6);
        xt[i] = (r < N_NODES) ? xbuf[(size_t)base * 64 + i] : 0.f;
    }
    for (int i = tid; i < 64 * 64; i += 256) wb[i] = w1[i];
    __syncthreads();

    int wave = tid >> 6, lane = tid & 63;
    float bias = b1[lane];
    for (int rr = 0; rr < 16; ++rr) {
        int r = wave * 16 + rr;
        float acc = bias;
#pragma unroll
        for (int k = 0; k < 64; ++k) acc += xt[r * 64 + k] * wb[k * 64 + lane];
        yt[r * 64 + lane] = fmaxf(acc, 0.f);
    }
    __syncthreads();
    for (int i = tid; i < 64 * 64; i += 256) wb[i] = w2[i];
    __syncthreads();
    bias = b2[lane];
    for (int rr = 0; rr < 16; ++rr) {
        int r = wave * 16 + rr;
        float acc = bias;
#pragma unroll
        for (int k = 0; k < 64; ++k) acc += yt[r * 64 + k] * wb[k * 64 + lane];
        xt[r * 64 + lane] = fmaxf(acc, 0.f);
    }
    __syncthreads();
    for (int i = tid; i < 64 * 64; i += 256) wb[i] = w3[i];
    __syncthreads();
    bias = b3[lane];
    for (int rr = 0; rr < 16; ++rr) {
        int r = wave * 16 + rr;
        int gr = base + r;
        if (gr >= N_NODES) continue;
        float acc = bias;
#pragma unroll
        for (int k = 0; k < 64; ++k) acc += xt[r * 64 + k] * wb[k * 64 + lane];
        out[(size_t)gr * 64 + lane] = acc;
    }
}

extern "C" void kernel_launch(void* const* d_in, const int* in_sizes, int n_in,
                              void* d_out, int out_size, void* d_ws, size_t ws_size,
                              hipStream_t stream) {
    const float* h     = (const float*)d_in[0];
    const int*   ei    = (const int*)d_in[1];
    const float* att_w = (const float*)d_in[2];
    const float* att_b = (const float*)d_in[3];
    const float* w1    = (const float*)d_in[4];
    const float* b1    = (const float*)d_in[5];
    const float* w2    = (const float*)d_in[6];
    const float* b2    = (const float*)d_in[7];
    const float* w3    = (const float*)d_in[8];
    const float* b3    = (const float*)d_in[9];
    float* out = (float*)d_out;

    char* ws = (char*)d_ws;
    size_t off = 0;
    auto alloc = [&](size_t bytes) {
        char* p = ws + off;
        off = align_up(off + bytes, 256);
        return p;
    };
    int* deg  = (int*)alloc((size_t)N_NODES * 4);
    int* cur  = (int*)alloc((size_t)N_NODES * 4);
    int* offs = (int*)alloc((size_t)(N_NODES + 1) * 4);
    int* bsum = (int*)alloc(64 * 4);
    int* adj  = (int*)alloc((size_t)NDIR * 4);
    float* xbuf = (float*)alloc((size_t)N_NODES * D * 4);
    // total ws use: ~20.5 MB

    // zero deg (cur is seeded from offs later)
    hipMemsetAsync(deg, 0, (size_t)N_NODES * 4, stream);

    int nb = (N_NODES + 1023) / 1024;
    k_deg <<<(NDIR + 255) / 256, 256, 0, stream>>>(ei, deg);
    k_scan1<<<nb, 1024, 0, stream>>>(deg, offs, bsum);
    k_scan2<<<1, 64, 0, stream>>>(bsum, nb);
    k_scan3<<<(N_NODES + 255) / 256, 256, 0, stream>>>(offs, bsum, cur);
    k_seed <<<(N_NODES + 255) / 256, 256, 0, stream>>>(offs, cur);
    k_fill <<<(NDIR + 255) / 256, 256, 0, stream>>>(ei, cur, adj);
    k_agg  <<<(N_NODES * 64) / 256, 256, 0, stream>>>(h, offs, adj, att_w, att_b, xbuf);
    k_dense<<<(N_NODES + 63) / 64, 256, 0, stream>>>(xbuf, w1, b1, w2, b2, w3, b3, out);
}